// Round 4
// baseline (648.072 us; speedup 1.0000x reference)
//
#include <hip/hip_runtime.h>

typedef __bf16 bf16x8 __attribute__((ext_vector_type(8)));
typedef float f32x4 __attribute__((ext_vector_type(4)));
typedef unsigned int u32x4 __attribute__((ext_vector_type(4)));
typedef unsigned short u16x4 __attribute__((ext_vector_type(4)));

__device__ __forceinline__ unsigned short f2b(float f) {
  union { float f; unsigned int u; } a; a.f = f;
  unsigned int u = a.u;
  u += 0x7fffu + ((u >> 16) & 1u);   // round-to-nearest-even
  return (unsigned short)(u >> 16);
}

#define LDW 136  // padded LDS row stride in bf16 elems (+8 keeps 16B align)
#define G   4    // samples per block (software pipeline depth ~2)

// owa: Wa in MFMA B-fragment order [mp][kk][lane][8] -> stage-2 weight reads are
//      contiguous 1KB wave-loads. owb: Wb row-major bf16.
__global__ void prep_weights(const float* __restrict__ wa,
                             const float* __restrict__ wb,
                             unsigned short* __restrict__ owa,
                             unsigned short* __restrict__ owb) {
  int t = blockIdx.x * 256 + threadIdx.x;           // 0..32767
  if (t < 16384) {
    int j    = t & 7;
    int lane = (t >> 3) & 63;
    int kk   = (t >> 9) & 3;
    int mp   = t >> 11;                              // 0..7
    int quad = lane >> 4, l16 = lane & 15;
    // B[k][n] = Wa[n][k];  n = mp*16+l16 (Y row), k = kk*32 + quad*8 + j
    owa[t] = f2b(wa[(mp * 16 + l16) * 128 + kk * 32 + quad * 8 + j]);
  } else {
    int u = t - 16384;
    owb[u] = f2b(wb[u]);
  }
}

// One block = G samples, 512 threads = 8 waves; wave w owns output column tile w.
// Y = Wa * (M * Wb^T) + bias,  M = row-major reshape of x[n] to 128x128.
// Software pipeline (T14): while stage1/stage2 compute sample s, sample s+1's x
// rides in 8 f32x4 registers (global loads in flight); after the uf-hoist barrier
// frees Mlds, convert+write M(s+1) in place, issue loads for s+2, then stage2(s).
// All barrier-guarding conditions are block-uniform (blockIdx/s/G/Ntot only).
__global__ __launch_bounds__(512, 4)
void krone_kernel(const float* __restrict__ x,
                  const unsigned short* __restrict__ waf,  // bf16 bits, frag order [8][4][64][8]
                  const unsigned short* __restrict__ wb,   // bf16 bits, [128][128]
                  const float* __restrict__ bias,
                  float* __restrict__ out, int Ntot) {
  __shared__ unsigned short Mlds[128 * LDW];   // M(s), then U^T(s) in place, then M(s+1)

  const int tid  = threadIdx.x;
  const int lane = tid & 63;
  const int w    = tid >> 6;   // wave id == col tile (0..7)
  const int quad = lane >> 4;  // 0..3
  const int l16  = lane & 15;
  const int n0   = blockIdx.x * G;
  const int ns   = (Ntot - n0 < G) ? (Ntot - n0) : G;   // samples this block (uniform)

  // per-thread staging geometry (loop-invariant)
  const int sr = tid >> 5;             // M row for f32x4 chunk 0 (rows step by 16 per i)
  const int sc = (tid & 31) << 2;      // M col

  // ---- hoist Wb B-fragments (block-invariant, amortized over G samples) ----
  bf16x8 wbf[4];
  {
    const unsigned short* wbr = wb + (w * 16 + l16) * 128 + quad * 8;
    #pragma unroll
    for (int kk = 0; kk < 4; ++kk)
      wbf[kk] = __builtin_bit_cast(bf16x8, *(const u32x4*)(wbr + kk * 32));
  }

  // ---- prologue: load+stage M(0); issue loads for sample 1 ----
  f32x4 R[8];                                   // in-flight x tile (statically indexed)
  {
    const float* xr = x + (size_t)n0 * 16384 + (tid << 2);
    #pragma unroll
    for (int i = 0; i < 8; ++i)
      R[i] = *(const f32x4*)(xr + (i << 11));
  }
  #pragma unroll
  for (int i = 0; i < 8; ++i) {
    u16x4 h;
    h[0] = f2b(R[i][0]); h[1] = f2b(R[i][1]); h[2] = f2b(R[i][2]); h[3] = f2b(R[i][3]);
    *(u16x4*)&Mlds[(sr + i * 16) * LDW + sc] = h;
  }
  if (1 < ns) {
    const float* xr = x + (size_t)(n0 + 1) * 16384 + (tid << 2);
    #pragma unroll
    for (int i = 0; i < 8; ++i)
      R[i] = *(const f32x4*)(xr + (i << 11));
  }
  __syncthreads();   // M(0) staged

  #pragma unroll 1
  for (int s = 0; s < ns; ++s) {
    const int n = n0 + s;

    // ---- stage 1: U = M * Wb^T, cols [16w,16w+16); packed results in regs ----
    u16x4 ur[8];
    #pragma unroll
    for (int m = 0; m < 8; ++m) {
      f32x4 acc = {0.f, 0.f, 0.f, 0.f};
      const unsigned short* mr = &Mlds[(m * 16 + l16) * LDW + quad * 8];
      #pragma unroll
      for (int kk = 0; kk < 4; ++kk) {
        u32x4 ua = *(const u32x4*)(mr + kk * 32);
        acc = __builtin_amdgcn_mfma_f32_16x16x32_bf16(
                __builtin_bit_cast(bf16x8, ua), wbf[kk], acc, 0, 0, 0);
      }
      // acc[i] = U[m*16 + quad*4 + i][16w + l16]
      u16x4 h;
      h[0] = f2b(acc[0]); h[1] = f2b(acc[1]); h[2] = f2b(acc[2]); h[3] = f2b(acc[3]);
      ur[m] = h;
    }

    __syncthreads();   // A: all waves done reading M(s)

    // ---- write U^T stripe in place; hoist own A-fragments (no barrier needed) ----
    #pragma unroll
    for (int m = 0; m < 8; ++m)
      *(u16x4*)&Mlds[(w * 16 + l16) * LDW + m * 16 + quad * 4] = ur[m];
    bf16x8 uf[4];
    {
      const unsigned short* utr = &Mlds[(w * 16 + l16) * LDW + quad * 8];
      #pragma unroll
      for (int kk = 0; kk < 4; ++kk)
        uf[kk] = __builtin_bit_cast(bf16x8, *(const u32x4*)(utr + kk * 32));
    }

    __syncthreads();   // B: all waves hoisted U^T(s) -> Mlds is free

    // ---- stage M(s+1) from in-flight regs; issue loads for s+2 ----
    if (s + 1 < ns) {
      #pragma unroll
      for (int i = 0; i < 8; ++i) {
        u16x4 h;
        h[0] = f2b(R[i][0]); h[1] = f2b(R[i][1]); h[2] = f2b(R[i][2]); h[3] = f2b(R[i][3]);
        *(u16x4*)&Mlds[(sr + i * 16) * LDW + sc] = h;
      }
      if (s + 2 < ns) {
        const float* xr = x + (size_t)(n + 2) * 16384 + (tid << 2);
        #pragma unroll
        for (int i = 0; i < 8; ++i)
          R[i] = *(const f32x4*)(xr + (i << 11));
      }
    }

    // ---- stage 2: D = U^T x Wa^T (no Mlds access); fused bias, f32x4 stores ----
    float* orow = out + (size_t)n * 16384;
    const unsigned short* wafl = waf + lane * 8;
    #pragma unroll
    for (int mp = 0; mp < 8; ++mp) {
      f32x4 acc = {0.f, 0.f, 0.f, 0.f};
      #pragma unroll
      for (int kk = 0; kk < 4; ++kk) {
        u32x4 ub = *(const u32x4*)(wafl + (mp * 4 + kk) * 512);   // contiguous 1KB wave-load
        acc = __builtin_amdgcn_mfma_f32_16x16x32_bf16(
                uf[kk], __builtin_bit_cast(bf16x8, ub), acc, 0, 0, 0);
      }
      int r  = mp * 16 + l16;            // Y row
      int c0 = w * 16 + quad * 4;        // Y col
      f32x4 b = *(const f32x4*)(bias + r * 128 + c0);
      *(f32x4*)(orow + r * 128 + c0) = acc + b;
    }

    __syncthreads();   // C: M(s+1) writes visible before next iteration's stage1
  }
}

extern "C" void kernel_launch(void* const* d_in, const int* in_sizes, int n_in,
                              void* d_out, int out_size, void* d_ws, size_t ws_size,
                              hipStream_t stream) {
  const float* x  = (const float*)d_in[0];
  const float* wa = (const float*)d_in[1];
  const float* wb = (const float*)d_in[2];
  const float* bs = (const float*)d_in[3];
  float* out = (float*)d_out;

  unsigned short* wsa = (unsigned short*)d_ws;      // 32 KB bf16 Wa (fragment order)
  unsigned short* wsb = wsa + 128 * 128;            // 32 KB bf16 Wb (row-major)

  int N = in_sizes[0] / 16384;                      // 4096

  prep_weights<<<128, 256, 0, stream>>>(wa, wb, wsa, wsb);
  int nblk = (N + G - 1) / G;
  krone_kernel<<<nblk, 512, 0, stream>>>(x, wsa, wsb, bs, out, N);
}

// Round 5
// 493.898 us; speedup vs baseline: 1.3122x; 1.3122x over previous
//
#include <hip/hip_runtime.h>

typedef __bf16 bf16x8 __attribute__((ext_vector_type(8)));
typedef float f32x4 __attribute__((ext_vector_type(4)));
typedef unsigned int u32x4 __attribute__((ext_vector_type(4)));
typedef unsigned short u16x4 __attribute__((ext_vector_type(4)));

__device__ __forceinline__ unsigned short f2b(float f) {
  union { float f; unsigned int u; } a; a.f = f;
  unsigned int u = a.u;
  u += 0x7fffu + ((u >> 16) & 1u);   // round-to-nearest-even
  return (unsigned short)(u >> 16);
}

#define LDW 136  // padded LDS row stride in bf16 elems (+8 keeps 16B align)

// owa: Wa in MFMA B-fragment order [mp][kk][lane][8] -> stage-2 weight reads are
//      contiguous 1KB wave-loads. owb: Wb row-major bf16.
__global__ void prep_weights(const float* __restrict__ wa,
                             const float* __restrict__ wb,
                             unsigned short* __restrict__ owa,
                             unsigned short* __restrict__ owb) {
  int t = blockIdx.x * 256 + threadIdx.x;           // 0..32767
  if (t < 16384) {
    int j    = t & 7;
    int lane = (t >> 3) & 63;
    int kk   = (t >> 9) & 3;
    int mp   = t >> 11;                              // 0..7
    int quad = lane >> 4, l16 = lane & 15;
    // B[k][n] = Wa[n][k];  n = mp*16+l16 (Y row), k = kk*32 + quad*8 + j
    owa[t] = f2b(wa[(mp * 16 + l16) * 128 + kk * 32 + quad * 8 + j]);
  } else {
    int u = t - 16384;
    owb[u] = f2b(wb[u]);
  }
}

// One block = one sample (traffic-clean R2 schedule). 512 threads = 8 waves; wave w
// owns output column tile w. Y = Wa * (M * Wb^T) + bias, M = reshape(x[n], 128x128).
//
// vs R2: the x-load prologue is SPLIT (all 8 f32x4 loads issued before any convert)
// so the compiler keeps 8 loads in flight (R2's fused loop at VGPR=36 exposed the
// ~900cy HBM latency twice). wbf loads issue under the x-wait. Output uses
// nontemporal stores so 256MB of out doesn't evict x from L3 between iterations.
__global__ __launch_bounds__(512, 4)
void krone_kernel(const float* __restrict__ x,
                  const unsigned short* __restrict__ waf,  // bf16 bits, frag order [8][4][64][8]
                  const unsigned short* __restrict__ wb,   // bf16 bits, [128][128]
                  const float* __restrict__ bias,
                  float* __restrict__ out) {
  __shared__ unsigned short Mlds[128 * LDW];   // M, then U^T in place

  const int tid  = threadIdx.x;
  const int lane = tid & 63;
  const int w    = tid >> 6;   // wave id == col tile (0..7)
  const int quad = lane >> 4;  // 0..3
  const int l16  = lane & 15;

  // per-thread staging geometry
  const int sr = tid >> 5;             // M row for chunk 0 (rows step by 16 per i)
  const int sc = (tid & 31) << 2;      // M col

  // ---- issue ALL x loads first (8 in flight), then wbf under the wait ----
  f32x4 R[8];                                   // statically indexed -> VGPRs
  {
    const float* xr = x + (size_t)blockIdx.x * 16384 + (tid << 2);
    #pragma unroll
    for (int i = 0; i < 8; ++i)
      R[i] = *(const f32x4*)(xr + (i << 11));
  }

  bf16x8 wbf[4];
  {
    const unsigned short* wbr = wb + (w * 16 + l16) * 128 + quad * 8;
    #pragma unroll
    for (int kk = 0; kk < 4; ++kk)
      wbf[kk] = __builtin_bit_cast(bf16x8, *(const u32x4*)(wbr + kk * 32));
  }

  // ---- convert fp32 -> bf16 and stage M into LDS ----
  #pragma unroll
  for (int i = 0; i < 8; ++i) {
    u16x4 h;
    h[0] = f2b(R[i][0]); h[1] = f2b(R[i][1]); h[2] = f2b(R[i][2]); h[3] = f2b(R[i][3]);
    *(u16x4*)&Mlds[(sr + i * 16) * LDW + sc] = h;   // 8B write, conflict-free
  }

  __syncthreads();   // barrier 1: M fully staged

  // ---- stage 1: U = M * Wb^T, cols [16w,16w+16); packed results stay in regs ----
  u16x4 ur[8];
  #pragma unroll
  for (int m = 0; m < 8; ++m) {
    f32x4 acc = {0.f, 0.f, 0.f, 0.f};
    const unsigned short* mr = &Mlds[(m * 16 + l16) * LDW + quad * 8];
    #pragma unroll
    for (int kk = 0; kk < 4; ++kk) {
      u32x4 ua = *(const u32x4*)(mr + kk * 32);
      acc = __builtin_amdgcn_mfma_f32_16x16x32_bf16(
              __builtin_bit_cast(bf16x8, ua), wbf[kk], acc, 0, 0, 0);
    }
    // acc[i] = U[m*16 + quad*4 + i][16w + l16]
    u16x4 h;
    h[0] = f2b(acc[0]); h[1] = f2b(acc[1]); h[2] = f2b(acc[2]); h[3] = f2b(acc[3]);
    ur[m] = h;
  }

  __syncthreads();   // barrier 2: all waves done READING M; safe to overwrite in place

  // ---- write U^T stripe into the SAME buffer; hoist own A-fragments (no barrier) ----
  #pragma unroll
  for (int m = 0; m < 8; ++m)
    *(u16x4*)&Mlds[(w * 16 + l16) * LDW + m * 16 + quad * 4] = ur[m];
  bf16x8 uf[4];
  {
    const unsigned short* utr = &Mlds[(w * 16 + l16) * LDW + quad * 8];
    #pragma unroll
    for (int kk = 0; kk < 4; ++kk)
      uf[kk] = __builtin_bit_cast(bf16x8, *(const u32x4*)(utr + kk * 32));
  }

  // ---- stage 2: D = U^T x Wa^T; fused bias; nontemporal f32x4 stores ----
  float* orow = out + (size_t)blockIdx.x * 16384;
  const unsigned short* wafl = waf + lane * 8;
  #pragma unroll
  for (int mp = 0; mp < 8; ++mp) {
    f32x4 acc = {0.f, 0.f, 0.f, 0.f};
    #pragma unroll
    for (int kk = 0; kk < 4; ++kk) {
      u32x4 ub = *(const u32x4*)(wafl + (mp * 4 + kk) * 512);   // contiguous 1KB wave-load
      acc = __builtin_amdgcn_mfma_f32_16x16x32_bf16(
              uf[kk], __builtin_bit_cast(bf16x8, ub), acc, 0, 0, 0);
    }
    int r  = mp * 16 + l16;            // Y row
    int c0 = w * 16 + quad * 4;        // Y col
    f32x4 b = *(const f32x4*)(bias + r * 128 + c0);
    f32x4 y = acc + b;
    __builtin_nontemporal_store(y, (f32x4*)(orow + r * 128 + c0));  // 16B NT store
  }
}

extern "C" void kernel_launch(void* const* d_in, const int* in_sizes, int n_in,
                              void* d_out, int out_size, void* d_ws, size_t ws_size,
                              hipStream_t stream) {
  const float* x  = (const float*)d_in[0];
  const float* wa = (const float*)d_in[1];
  const float* wb = (const float*)d_in[2];
  const float* bs = (const float*)d_in[3];
  float* out = (float*)d_out;

  unsigned short* wsa = (unsigned short*)d_ws;      // 32 KB bf16 Wa (fragment order)
  unsigned short* wsb = wsa + 128 * 128;            // 32 KB bf16 Wb (row-major)

  int N = in_sizes[0] / 16384;                      // 4096

  prep_weights<<<128, 256, 0, stream>>>(wa, wb, wsa, wsb);
  krone_kernel<<<N, 512, 0, stream>>>(x, wsa, wsb, bs, out);
}